// Round 6
// baseline (2612.738 us; speedup 1.0000x reference)
//
#include <hip/hip_runtime.h>
#include <math.h>

static constexpr int NU    = 100000;
static constexpr int NI    = 50000;
static constexpr int NEDGE = 1600000;
static constexpr int DIM   = 128;

// grid-role constants
static constexpr int CB   = 1792;                // count blocks in k1 (resident-mix tuned for 8 blk/CU)
static constexpr int GF   = (NU + 127) / 128;    // 782  gemm128 blocks (NU)
static constexpr int GV   = (NI + 127) / 128;    // 391  gemm128 blocks (NI)
static constexpr int GF2  = (NU + 63) / 64;      // 1563 gemm64 blocks (NU)
static constexpr int GV2  = (NI + 63) / 64;      // 782  gemm64 blocks (NI)
static constexpr int FB   = 512;                 // fill blocks per relation
static constexpr int AGU  = (NU + 3) / 4;        // 25000 agg blocks (user dst)
static constexpr int AGI  = (NI + 3) / 4;        // 12500 agg blocks (item dst)

// ---------------- count + rank (atomic returns old value = rank within dst) ----------------
__device__ __forceinline__ void count_rel(const int* __restrict__ src, const int* __restrict__ dst,
                                          int* __restrict__ deg_s, int* __restrict__ deg_d,
                                          int* __restrict__ rank, int blk, int nblk) {
  const int nchunk = NEDGE / 4;
  const int stride = nblk * 256;
  for (int c = blk * 256 + threadIdx.x; c < nchunk; c += stride) {
    int4 s = ((const int4*)src)[c];
    int4 d = ((const int4*)dst)[c];
    atomicAdd(&deg_s[s.x], 1);
    atomicAdd(&deg_s[s.y], 1);
    atomicAdd(&deg_s[s.z], 1);
    atomicAdd(&deg_s[s.w], 1);
    int4 r;
    r.x = atomicAdd(&deg_d[d.x], 1);
    r.y = atomicAdd(&deg_d[d.y], 1);
    r.z = atomicAdd(&deg_d[d.z], 1);
    r.w = atomicAdd(&deg_d[d.w], 1);
    ((int4*)rank)[c] = r;
  }
}

// ---------------- atomic-free CSR fill (pure scatter) ----------------
__device__ __forceinline__ void fill_rel(const int* __restrict__ src, const int* __restrict__ dst,
                                         const int* __restrict__ rank, const int* __restrict__ rp,
                                         int* __restrict__ csr, int blk, int nblk) {
  const int nchunk = NEDGE / 4;
  const int stride = nblk * 256;
  for (int c = blk * 256 + threadIdx.x; c < nchunk; c += stride) {
    int4 s = ((const int4*)src)[c];
    int4 d = ((const int4*)dst)[c];
    int4 r = ((const int4*)rank)[c];
    csr[rp[d.x] + r.x] = s.x;
    csr[rp[d.y] + r.y] = s.y;
    csr[rp[d.z] + r.z] = s.z;
    csr[rp[d.w] + r.w] = s.w;
  }
}

// ---------------- fp32 GEMM 128-tile (8x8/thread, high VGPR, standalone) ----------------
__device__ __forceinline__ void gemm_body(const float* __restrict__ A, const float* __restrict__ W,
                                          float* __restrict__ C, int M, int blk) {
  static __shared__ float As[16][132];
  static __shared__ float Bs[16][128];
  const int tid = threadIdx.x;
  const int tx = tid & 15, ty = tid >> 4;
  const int row0 = blk * 128;
  float acc[8][8];
#pragma unroll
  for (int r = 0; r < 8; ++r)
#pragma unroll
    for (int c = 0; c < 8; ++c) acc[r][c] = 0.f;

  for (int kk = 0; kk < DIM; kk += 16) {
#pragma unroll
    for (int p = 0; p < 2; ++p) {
      int r = (tid >> 2) + p * 64;
      int kc = (tid & 3) * 4;
      float4 a = make_float4(0.f, 0.f, 0.f, 0.f);
      int row = row0 + r;
      if (row < M) a = *(const float4*)(A + (size_t)row * DIM + kk + kc);
      As[kc + 0][r] = a.x; As[kc + 1][r] = a.y; As[kc + 2][r] = a.z; As[kc + 3][r] = a.w;
    }
    {
      const float4* srcp = (const float4*)(W + kk * DIM);
      float4* dstp = (float4*)(&Bs[0][0]);
      dstp[tid]       = srcp[tid];
      dstp[tid + 256] = srcp[tid + 256];
    }
    __syncthreads();
#pragma unroll
    for (int k = 0; k < 16; ++k) {
      float a[8], b[8];
      *(float4*)&a[0] = *(const float4*)&As[k][ty * 8];
      *(float4*)&a[4] = *(const float4*)&As[k][ty * 8 + 4];
      *(float4*)&b[0] = *(const float4*)&Bs[k][tx * 8];
      *(float4*)&b[4] = *(const float4*)&Bs[k][tx * 8 + 4];
#pragma unroll
      for (int r = 0; r < 8; ++r)
#pragma unroll
        for (int c = 0; c < 8; ++c) acc[r][c] += a[r] * b[c];
    }
    __syncthreads();
  }
#pragma unroll
  for (int r = 0; r < 8; ++r) {
    int row = row0 + ty * 8 + r;
    if (row < M) {
      float4* cp = (float4*)(C + (size_t)row * DIM + tx * 8);
      cp[0] = make_float4(acc[r][0], acc[r][1], acc[r][2], acc[r][3]);
      cp[1] = make_float4(acc[r][4], acc[r][5], acc[r][6], acc[r][7]);
    }
  }
}

// ---------------- fp32 GEMM 64-tile (4x8/thread, <=64 VGPR, for count-fused k1) ----------------
__device__ __forceinline__ void gemm64_body(const float* __restrict__ A, const float* __restrict__ W,
                                            float* __restrict__ C, int M, int blk) {
  static __shared__ float As6[16][68];
  static __shared__ float Bs6[16][128];
  const int tid = threadIdx.x;
  const int tx = tid & 15, ty = tid >> 4;
  const int row0 = blk * 64;
  float acc[4][8];
#pragma unroll
  for (int r = 0; r < 4; ++r)
#pragma unroll
    for (int c = 0; c < 8; ++c) acc[r][c] = 0.f;

  for (int kk = 0; kk < DIM; kk += 16) {
    {
      int r = tid >> 2;
      int kc = (tid & 3) * 4;
      float4 a = make_float4(0.f, 0.f, 0.f, 0.f);
      int row = row0 + r;
      if (row < M) a = *(const float4*)(A + (size_t)row * DIM + kk + kc);
      As6[kc + 0][r] = a.x; As6[kc + 1][r] = a.y; As6[kc + 2][r] = a.z; As6[kc + 3][r] = a.w;
    }
    {
      const float4* srcp = (const float4*)(W + kk * DIM);
      float4* dstp = (float4*)(&Bs6[0][0]);
      dstp[tid]       = srcp[tid];
      dstp[tid + 256] = srcp[tid + 256];
    }
    __syncthreads();
#pragma unroll
    for (int k = 0; k < 16; ++k) {
      float a[4], b[8];
      *(float4*)&a[0] = *(const float4*)&As6[k][ty * 4];
      *(float4*)&b[0] = *(const float4*)&Bs6[k][tx * 8];
      *(float4*)&b[4] = *(const float4*)&Bs6[k][tx * 8 + 4];
#pragma unroll
      for (int r = 0; r < 4; ++r)
#pragma unroll
        for (int c = 0; c < 8; ++c) acc[r][c] += a[r] * b[c];
    }
    __syncthreads();
  }
#pragma unroll
  for (int r = 0; r < 4; ++r) {
    int row = row0 + ty * 4 + r;
    if (row < M) {
      float4* cp = (float4*)(C + (size_t)row * DIM + tx * 8);
      cp[0] = make_float4(acc[r][0], acc[r][1], acc[r][2], acc[r][3]);
      cp[1] = make_float4(acc[r][4], acc[r][5], acc[r][6], acc[r][7]);
    }
  }
}

// ---------------- aggregation rows: one wave per dst row, float4 half-wave gathers ----------------
// MODE 0: out = agg ; MODE 1: out = maybe_relu(scale*(out_prev+agg+b1+b2)) ; MODE 2: out = maybe_relu(scale*(agg+b1))
template <int MODE, bool RELU>
__device__ __forceinline__ void agg_rows(const float* __restrict__ h, const int* __restrict__ rp,
                                         const int* __restrict__ csr, const float* __restrict__ inv_s,
                                         const float* __restrict__ inv_d, float* __restrict__ out,
                                         int n_dst, float scale, const float* __restrict__ b1,
                                         const float* __restrict__ b2, int blk) {
  const int lane = threadIdx.x & 63;
  const int half = lane >> 5;     // 0/1: which 4-edge group of each 8
  const int sl   = lane & 31;     // float4 column group (32*4 = 128 floats)
  const int row = blk * 4 + (threadIdx.x >> 6);
  if (row >= n_dst) return;
  const int e0 = rp[row], e1 = rp[row + 1];
  float4 acc = make_float4(0.f, 0.f, 0.f, 0.f);
  for (int base = e0; base < e1; base += 64) {
    const int rem = e1 - base;
    const int m = rem < 64 ? rem : 64;
    int s_l = 0; float w_l = 0.f;
    if (lane < m) { s_l = csr[base + lane]; w_l = inv_s[s_l]; }
    int j = 0;
    for (; j + 8 <= m; j += 8) {
      const int eb = j + half * 4;
      int s0 = __shfl(s_l, eb),     s1 = __shfl(s_l, eb + 1);
      int s2 = __shfl(s_l, eb + 2), s3 = __shfl(s_l, eb + 3);
      float w0 = __shfl(w_l, eb),     w1 = __shfl(w_l, eb + 1);
      float w2 = __shfl(w_l, eb + 2), w3 = __shfl(w_l, eb + 3);
      float4 v0 = ((const float4*)(h + (size_t)s0 * DIM))[sl];
      float4 v1 = ((const float4*)(h + (size_t)s1 * DIM))[sl];
      float4 v2 = ((const float4*)(h + (size_t)s2 * DIM))[sl];
      float4 v3 = ((const float4*)(h + (size_t)s3 * DIM))[sl];
      acc.x += w0 * v0.x + w1 * v1.x + w2 * v2.x + w3 * v3.x;
      acc.y += w0 * v0.y + w1 * v1.y + w2 * v2.y + w3 * v3.y;
      acc.z += w0 * v0.z + w1 * v1.z + w2 * v2.z + w3 * v3.z;
      acc.w += w0 * v0.w + w1 * v1.w + w2 * v2.w + w3 * v3.w;
    }
    // tail: pairs, half-wave split; lanes >= m hold s=0,w=0 so OOB e is harmless
    for (; j < m; j += 2) {
      const int e = j + half;   // j even, j <= 62 -> e <= 63
      int s = __shfl(s_l, e);
      float w = __shfl(w_l, e);
      float4 v = ((const float4*)(h + (size_t)s * DIM))[sl];
      acc.x += w * v.x; acc.y += w * v.y; acc.z += w * v.z; acc.w += w * v.w;
    }
  }
  // combine the two half-wave partial sums
  float4 o;
  o.x = __shfl(acc.x, lane ^ 32);
  o.y = __shfl(acc.y, lane ^ 32);
  o.z = __shfl(acc.z, lane ^ 32);
  o.w = __shfl(acc.w, lane ^ 32);
  acc.x += o.x; acc.y += o.y; acc.z += o.z; acc.w += o.w;

  if (half == 0) {
    const float invd = inv_d[row];
    float4 r = make_float4(acc.x * invd, acc.y * invd, acc.z * invd, acc.w * invd);
    float4* op4 = (float4*)(out + (size_t)row * DIM);
    if (MODE == 0) {
      op4[sl] = r;
    } else {
      float4 bv = make_float4(0.f, 0.f, 0.f, 0.f);
      if (b1) { float4 b = ((const float4*)b1)[sl]; bv.x += b.x; bv.y += b.y; bv.z += b.z; bv.w += b.w; }
      if (b2) { float4 b = ((const float4*)b2)[sl]; bv.x += b.x; bv.y += b.y; bv.z += b.z; bv.w += b.w; }
      float4 p = make_float4(0.f, 0.f, 0.f, 0.f);
      if (MODE == 1) p = op4[sl];
      float4 v;
      v.x = scale * (p.x + r.x + bv.x);
      v.y = scale * (p.y + r.y + bv.y);
      v.z = scale * (p.z + r.z + bv.z);
      v.w = scale * (p.w + r.w + bv.w);
      if (RELU) {
        v.x = fmaxf(v.x, 0.f); v.y = fmaxf(v.y, 0.f);
        v.z = fmaxf(v.z, 0.f); v.w = fmaxf(v.w, 0.f);
      }
      op4[sl] = v;
    }
  }
}

// ---------------- single-block scan body ----------------
__device__ void scan_body(const int* __restrict__ deg, int n, int* __restrict__ rp) {
  static __shared__ int wsum[16];
  static __shared__ int carry_s;
  const int tid = threadIdx.x, lane = tid & 63, wid = tid >> 6;
  if (tid == 0) carry_s = 0;
  __syncthreads();
  for (int base = 0; base < n; base += 4096) {
    int i0 = base + tid * 4;
    int v0 = 0, v1 = 0, v2 = 0, v3 = 0;
    if (i0 + 3 < n) {
      int4 t = *(const int4*)(deg + i0);
      v0 = t.x; v1 = t.y; v2 = t.z; v3 = t.w;
    } else {
      if (i0     < n) v0 = deg[i0];
      if (i0 + 1 < n) v1 = deg[i0 + 1];
      if (i0 + 2 < n) v2 = deg[i0 + 2];
    }
    int s0 = v0, s1 = s0 + v1, s2 = s1 + v2, s3 = s2 + v3;
    int tot = s3;
    int x = tot;
#pragma unroll
    for (int d2 = 1; d2 < 64; d2 <<= 1) { int y = __shfl_up(x, d2); if (lane >= d2) x += y; }
    if (lane == 63) wsum[wid] = x;
    __syncthreads();
    if (wid == 0) {
      int s = (lane < 16) ? wsum[lane] : 0;
#pragma unroll
      for (int d2 = 1; d2 < 16; d2 <<= 1) { int y = __shfl_up(s, d2); if (lane >= d2) s += y; }
      if (lane < 16) wsum[lane] = s;
    }
    __syncthreads();
    int carry = carry_s;
    int woff = (wid > 0) ? wsum[wid - 1] : 0;
    int base_excl = carry + woff + (x - tot);
    if (i0     < n) rp[i0]     = base_excl;
    if (i0 + 1 < n) rp[i0 + 1] = base_excl + s0;
    if (i0 + 2 < n) rp[i0 + 2] = base_excl + s1;
    if (i0 + 3 < n) rp[i0 + 3] = base_excl + s2;
    __syncthreads();
    if (tid == 0) carry_s = carry + wsum[15];
    __syncthreads();
  }
  if (tid == 0) rp[n] = carry_s;
}

// =================== kernels ===================

// K1: count all 3 relations (blocks [0,CB)) || layer-1 GEMMs (64-tile, <=64 VGPR for occupancy)
__global__ __launch_bounds__(256, 8) void k1_kernel(
    const int* f_src, const int* f_dst, int* deg_fs, int* deg_fd, int* rank_f,
    const int* r_src, const int* r_dst, int* deg_rs, int* deg_rd, int* rank_r,
    const int* v_src, const int* v_dst, int* deg_vs, int* deg_vd, int* rank_v,
    const float* x_user, const float* x_item,
    const float* W1f, const float* W1v, const float* W1r,
    float* h_f, float* h_v, float* h_r) {
  int b = blockIdx.x;
  if (b < CB) {
    count_rel(f_src, f_dst, deg_fs, deg_fd, rank_f, b, CB);
    count_rel(r_src, r_dst, deg_rs, deg_rd, rank_r, b, CB);
    count_rel(v_src, v_dst, deg_vs, deg_vd, rank_v, b, CB);
  } else if (b < CB + GF2) {
    gemm64_body(x_user, W1f, h_f, NU, b - CB);
  } else if (b < CB + GF2 + GV2) {
    gemm64_body(x_item, W1v, h_v, NI, b - CB - GF2);
  } else {
    gemm64_body(x_user, W1r, h_r, NU, b - CB - GF2 - GV2);
  }
}

__global__ __launch_bounds__(1024) void scan3_kernel(const int* deg_fd, int* rp_f,
                                                     const int* deg_rd, int* rp_r,
                                                     const int* deg_vd, int* rp_v) {
  if (blockIdx.x == 0)      scan_body(deg_fd, NU, rp_f);
  else if (blockIdx.x == 1) scan_body(deg_rd, NI, rp_r);
  else                      scan_body(deg_vd, NU, rp_v);
}

// in-place int degree -> float 1/sqrt(deg)
__global__ void inv_sqrt_kernel(int* __restrict__ p, int n) {
  int i = blockIdx.x * blockDim.x + threadIdx.x;
  if (i < n) {
    int v = p[i];
    float f = (v > 0) ? (1.0f / sqrtf((float)v)) : 0.0f;
    p[i] = __float_as_int(f);
  }
}

__global__ __launch_bounds__(256) void fill_one_kernel(const int* src, const int* dst,
                                                       const int* rank, const int* rp, int* csr) {
  fill_rel(src, dst, rank, rp, csr, blockIdx.x, gridDim.x);
}

// K4: fill_v || fill_r || agg1_f (h_f -> u, MODE0)
__global__ __launch_bounds__(256) void k4_kernel(
    const int* v_src, const int* v_dst, const int* rank_v, const int* rp_v, int* csr_v,
    const int* r_src, const int* r_dst, const int* rank_r, const int* rp_r, int* csr_r,
    const float* h_f, const int* rp_f, const int* csr_f,
    const float* inv_fs, const float* inv_fd, float* u) {
  int b = blockIdx.x;
  if (b < FB)          fill_rel(v_src, v_dst, rank_v, rp_v, csr_v, b, FB);
  else if (b < 2 * FB) fill_rel(r_src, r_dst, rank_r, rp_r, csr_r, b - FB, FB);
  else agg_rows<0, false>(h_f, rp_f, csr_f, inv_fs, inv_fd, u, NU, 1.0f, nullptr, nullptr, b - 2 * FB);
}

// K5: agg1_v (MODE1 relu -> u) || agg1_r (MODE2 relu -> it)
__global__ __launch_bounds__(256) void k5_kernel(
    const float* h_v, const int* rp_v, const int* csr_v, const float* inv_vs, const float* inv_vd,
    float* u, const float* b1f, const float* b1v,
    const float* h_r, const int* rp_r, const int* csr_r, const float* inv_rs, const float* inv_rd,
    float* it, const float* b1r) {
  int b = blockIdx.x;
  if (b < AGU) agg_rows<1, true>(h_v, rp_v, csr_v, inv_vs, inv_vd, u, NU, 0.5f, b1f, b1v, b);
  else         agg_rows<2, true>(h_r, rp_r, csr_r, inv_rs, inv_rd, it, NI, 1.0f, b1r, nullptr, b - AGU);
}

__global__ __launch_bounds__(256) void gemm_one_kernel(const float* A, const float* W, float* C, int M) {
  gemm_body(A, W, C, M, blockIdx.x);
}

// K7: g2v (it@W2v->h_v) || g2r (u@W2r->h_r) || agg2_f (h_f -> out_u, MODE0)
__global__ __launch_bounds__(256) void k7_kernel(
    const float* it, const float* W2v, float* h_v,
    const float* u,  const float* W2r, float* h_r,
    const float* h_f, const int* rp_f, const int* csr_f,
    const float* inv_fs, const float* inv_fd, float* out_u) {
  int b = blockIdx.x;
  if (b < GV)           gemm_body(it, W2v, h_v, NI, b);
  else if (b < GV + GF) gemm_body(u, W2r, h_r, NU, b - GV);
  else agg_rows<0, false>(h_f, rp_f, csr_f, inv_fs, inv_fd, out_u, NU, 1.0f, nullptr, nullptr, b - GV - GF);
}

// K8: agg2_v (MODE1 -> out_u) || agg2_r (MODE2 -> out_i), no relu
__global__ __launch_bounds__(256) void k8_kernel(
    const float* h_v, const int* rp_v, const int* csr_v, const float* inv_vs, const float* inv_vd,
    float* out_u, const float* b2f, const float* b2v,
    const float* h_r, const int* rp_r, const int* csr_r, const float* inv_rs, const float* inv_rd,
    float* out_i, const float* b2r) {
  int b = blockIdx.x;
  if (b < AGU) agg_rows<1, false>(h_v, rp_v, csr_v, inv_vs, inv_vd, out_u, NU, 0.5f, b2f, b2v, b);
  else         agg_rows<2, false>(h_r, rp_r, csr_r, inv_rs, inv_rd, out_i, NI, 1.0f, b2r, nullptr, b - AGU);
}

// standalone agg for fallback path
template <int MODE, bool RELU>
__global__ __launch_bounds__(256) void agg_kernel(const float* h, const int* rp, const int* csr,
                                                  const float* inv_s, const float* inv_d,
                                                  float* out, int n_dst, float scale,
                                                  const float* b1, const float* b2) {
  agg_rows<MODE, RELU>(h, rp, csr, inv_s, inv_d, out, n_dst, scale, b1, b2, blockIdx.x);
}

extern "C" void kernel_launch(void* const* d_in, const int* in_sizes, int n_in,
                              void* d_out, int out_size, void* d_ws, size_t ws_size,
                              hipStream_t stream) {
  const float* x_user = (const float*)d_in[0];
  const float* x_item = (const float*)d_in[1];
  const int* f_src = (const int*)d_in[2];
  const int* f_dst = (const int*)d_in[3];
  const int* r_src = (const int*)d_in[4];
  const int* r_dst = (const int*)d_in[5];
  const int* v_src = (const int*)d_in[6];
  const int* v_dst = (const int*)d_in[7];
  const float* W1f = (const float*)d_in[8];
  const float* W1r = (const float*)d_in[9];
  const float* W1v = (const float*)d_in[10];
  const float* W2f = (const float*)d_in[11];
  const float* W2r = (const float*)d_in[12];
  const float* W2v = (const float*)d_in[13];
  const float* b1f = (const float*)d_in[14];
  const float* b1r = (const float*)d_in[15];
  const float* b1v = (const float*)d_in[16];
  const float* b2f = (const float*)d_in[17];
  const float* b2r = (const float*)d_in[18];
  const float* b2v = (const float*)d_in[19];
  (void)in_sizes; (void)n_in; (void)out_size;

  char* ws = (char*)d_ws;
  size_t off = 0;
  auto alloc = [&](size_t bytes) {
    size_t o = off;
    off = (off + bytes + 511) & ~(size_t)511;
    return o;
  };
  // common layout (identical to round 5)
  size_t o_deg = alloc(4ull * (4 * NU + 2 * NI));
  size_t o_rpf = alloc(4ull * (NU + 1));
  size_t o_rpr = alloc(4ull * (NI + 1));
  size_t o_rpv = alloc(4ull * (NU + 1));
  size_t o_csf = alloc(4ull * NEDGE);
  size_t o_csr = alloc(4ull * NEDGE);
  size_t o_csv = alloc(4ull * NEDGE);
  size_t o_it  = alloc(4ull * NI * DIM);
  size_t o_hf  = alloc(4ull * NU * DIM);
  size_t o_u   = alloc(4ull * NU * DIM);
  size_t o_hv  = alloc(4ull * NI * DIM);
  size_t o_hr  = alloc(4ull * NU * DIM);
  size_t o_rkf = alloc(4ull * NEDGE);
  size_t o_rkr = alloc(4ull * NEDGE);
  size_t o_rkv = alloc(4ull * NEDGE);
  size_t big_need = off + 512;

  const bool big = (ws_size >= big_need);

  int* deg    = (int*)(ws + o_deg);
  int* deg_fs = deg;
  int* deg_fd = deg + NU;
  int* deg_rs = deg + 2 * NU;
  int* deg_rd = deg + 3 * NU;
  int* deg_vs = deg + 3 * NU + NI;
  int* deg_vd = deg + 3 * NU + 2 * NI;

  int* rp_f = (int*)(ws + o_rpf);
  int* rp_r = (int*)(ws + o_rpr);
  int* rp_v = (int*)(ws + o_rpv);
  int* csr_f = (int*)(ws + o_csf);
  int* csr_r = (int*)(ws + o_csr);
  int* csr_v = (int*)(ws + o_csv);
  float* it  = (float*)(ws + o_it);
  float* h_f = (float*)(ws + o_hf);
  float* u   = (float*)(ws + o_u);
  float* h_v = big ? (float*)(ws + o_hv) : h_f;
  float* h_r = big ? (float*)(ws + o_hr) : h_f;
  int* rank_f = big ? (int*)(ws + o_rkf) : (int*)(ws + o_u);
  int* rank_r = big ? (int*)(ws + o_rkr) : (int*)(ws + o_u) + NEDGE;
  int* rank_v = big ? (int*)(ws + o_rkv) : (int*)(ws + o_u) + 2 * NEDGE;

  float* out_u = (float*)d_out;
  float* out_i = out_u + (size_t)NU * DIM;

  const float* inv_fs = (const float*)deg_fs;
  const float* inv_fd = (const float*)deg_fd;
  const float* inv_rs = (const float*)deg_rs;
  const float* inv_rd = (const float*)deg_rd;
  const float* inv_vs = (const float*)deg_vs;
  const float* inv_vd = (const float*)deg_vd;

  hipMemsetAsync(deg, 0, 4ull * (4 * NU + 2 * NI), stream);

  if (big) {
    // K1: count x3 (1792 blocks, ~7168 waves at 8 blk/CU) || layer-1 GEMMs (64-tile)
    k1_kernel<<<CB + GF2 + GV2 + GF2, 256, 0, stream>>>(
        f_src, f_dst, deg_fs, deg_fd, rank_f,
        r_src, r_dst, deg_rs, deg_rd, rank_r,
        v_src, v_dst, deg_vs, deg_vd, rank_v,
        x_user, x_item, W1f, W1v, W1r, h_f, h_v, h_r);
    scan3_kernel<<<3, 1024, 0, stream>>>(deg_fd, rp_f, deg_rd, rp_r, deg_vd, rp_v);
    inv_sqrt_kernel<<<(4 * NU + 2 * NI + 1023) / 1024, 1024, 0, stream>>>(deg, 4 * NU + 2 * NI);
    fill_one_kernel<<<1024, 256, 0, stream>>>(f_src, f_dst, rank_f, rp_f, csr_f);
    // K4: fill_v || fill_r || agg1_f
    k4_kernel<<<2 * FB + AGU, 256, 0, stream>>>(
        v_src, v_dst, rank_v, rp_v, csr_v,
        r_src, r_dst, rank_r, rp_r, csr_r,
        h_f, rp_f, csr_f, inv_fs, inv_fd, u);
    // K5: agg1_v || agg1_r (finish layer 1)
    k5_kernel<<<AGU + AGI, 256, 0, stream>>>(
        h_v, rp_v, csr_v, inv_vs, inv_vd, u, b1f, b1v,
        h_r, rp_r, csr_r, inv_rs, inv_rd, it, b1r);
    // K6: g2f (fast 128-tile)
    gemm_one_kernel<<<GF, 256, 0, stream>>>(u, W2f, h_f, NU);
    // K7: g2v || g2r || agg2_f
    k7_kernel<<<GV + GF + AGU, 256, 0, stream>>>(
        it, W2v, h_v, u, W2r, h_r,
        h_f, rp_f, csr_f, inv_fs, inv_fd, out_u);
    // K8: agg2_v || agg2_r
    k8_kernel<<<AGU + AGI, 256, 0, stream>>>(
        h_v, rp_v, csr_v, inv_vs, inv_vd, out_u, b2f, b2v,
        h_r, rp_r, csr_r, inv_rs, inv_rd, out_i, b2r);
  } else {
    // fallback: single h buffer, ranks alias u (u written only after all fills)
    k1_kernel<<<CB, 256, 0, stream>>>(   // count roles only
        f_src, f_dst, deg_fs, deg_fd, rank_f,
        r_src, r_dst, deg_rs, deg_rd, rank_r,
        v_src, v_dst, deg_vs, deg_vd, rank_v,
        x_user, x_item, W1f, W1v, W1r, h_f, h_v, h_r);
    scan3_kernel<<<3, 1024, 0, stream>>>(deg_fd, rp_f, deg_rd, rp_r, deg_vd, rp_v);
    inv_sqrt_kernel<<<(4 * NU + 2 * NI + 1023) / 1024, 1024, 0, stream>>>(deg, 4 * NU + 2 * NI);
    fill_one_kernel<<<1024, 256, 0, stream>>>(f_src, f_dst, rank_f, rp_f, csr_f);
    fill_one_kernel<<<1024, 256, 0, stream>>>(v_src, v_dst, rank_v, rp_v, csr_v);
    fill_one_kernel<<<1024, 256, 0, stream>>>(r_src, r_dst, rank_r, rp_r, csr_r);
    gemm_one_kernel<<<GF, 256, 0, stream>>>(x_user, W1f, h_f, NU);
    agg_kernel<0, false><<<AGU, 256, 0, stream>>>(h_f, rp_f, csr_f, inv_fs, inv_fd, u, NU, 1.0f, nullptr, nullptr);
    gemm_one_kernel<<<GV, 256, 0, stream>>>(x_item, W1v, h_f, NI);
    agg_kernel<1, true><<<AGU, 256, 0, stream>>>(h_f, rp_v, csr_v, inv_vs, inv_vd, u, NU, 0.5f, b1f, b1v);
    gemm_one_kernel<<<GF, 256, 0, stream>>>(x_user, W1r, h_f, NU);
    agg_kernel<2, true><<<AGI, 256, 0, stream>>>(h_f, rp_r, csr_r, inv_rs, inv_rd, it, NI, 1.0f, b1r, nullptr);
    gemm_one_kernel<<<GF, 256, 0, stream>>>(u, W2f, h_f, NU);
    agg_kernel<0, false><<<AGU, 256, 0, stream>>>(h_f, rp_f, csr_f, inv_fs, inv_fd, out_u, NU, 1.0f, nullptr, nullptr);
    gemm_one_kernel<<<GV, 256, 0, stream>>>(it, W2v, h_f, NI);
    agg_kernel<1, false><<<AGU, 256, 0, stream>>>(h_f, rp_v, csr_v, inv_vs, inv_vd, out_u, NU, 0.5f, b2f, b2v);
    gemm_one_kernel<<<GF, 256, 0, stream>>>(u, W2r, h_f, NU);
    agg_kernel<2, false><<<AGI, 256, 0, stream>>>(h_f, rp_r, csr_r, inv_rs, inv_rd, out_i, NI, 1.0f, b2r, nullptr);
  }
}

// Round 11
// 1716.327 us; speedup vs baseline: 1.5223x; 1.5223x over previous
//
#include <hip/hip_runtime.h>
#include <math.h>

static constexpr int NU    = 100000;
static constexpr int NI    = 50000;
static constexpr int NEDGE = 1600000;
static constexpr int DIM   = 128;

static constexpr int C3  = 768;                 // count blocks per relation
static constexpr int F3  = 1024;                // fill blocks per relation
static constexpr int GF  = (NU + 127) / 128;    // 782 gemm blocks (NU)
static constexpr int GV  = (NI + 127) / 128;    // 391 gemm blocks (NI)
static constexpr int AGU = (NU + 3) / 4;        // 25000 agg blocks (user dst)
static constexpr int AGI = (NI + 3) / 4;        // 12500 agg blocks (item dst)

// ---------------- count + rank (dst atomic returns old value = rank) ----------------
__device__ __forceinline__ void count_rel(const int* __restrict__ src, const int* __restrict__ dst,
                                          int* __restrict__ deg_s, int* __restrict__ deg_d,
                                          int* __restrict__ rank, int blk, int nblk) {
  const int nchunk = NEDGE / 4;
  const int stride = nblk * 256;
  for (int c = blk * 256 + threadIdx.x; c < nchunk; c += stride) {
    int4 s = ((const int4*)src)[c];
    int4 d = ((const int4*)dst)[c];
    atomicAdd(&deg_s[s.x], 1);
    atomicAdd(&deg_s[s.y], 1);
    atomicAdd(&deg_s[s.z], 1);
    atomicAdd(&deg_s[s.w], 1);
    int4 r;
    r.x = atomicAdd(&deg_d[d.x], 1);
    r.y = atomicAdd(&deg_d[d.y], 1);
    r.z = atomicAdd(&deg_d[d.z], 1);
    r.w = atomicAdd(&deg_d[d.w], 1);
    ((int4*)rank)[c] = r;
  }
}

// ---------------- atomic-free CSR fill (pure scatter) ----------------
__device__ __forceinline__ void fill_rel(const int* __restrict__ src, const int* __restrict__ dst,
                                         const int* __restrict__ rank, const int* __restrict__ rp,
                                         int* __restrict__ csr, int blk, int nblk) {
  const int nchunk = NEDGE / 4;
  const int stride = nblk * 256;
  for (int c = blk * 256 + threadIdx.x; c < nchunk; c += stride) {
    int4 s = ((const int4*)src)[c];
    int4 d = ((const int4*)dst)[c];
    int4 r = ((const int4*)rank)[c];
    csr[rp[d.x] + r.x] = s.x;
    csr[rp[d.y] + r.y] = s.y;
    csr[rp[d.z] + r.z] = s.z;
    csr[rp[d.w] + r.w] = s.w;
  }
}

// ---------------- fp32 GEMM 128-tile (8x8/thread): C[M,128] = A[M,128] @ W[128,128] ----------------
__device__ __forceinline__ void gemm_body(const float* __restrict__ A, const float* __restrict__ W,
                                          float* __restrict__ C, int M, int blk) {
  static __shared__ float As[16][132];
  static __shared__ float Bs[16][128];
  const int tid = threadIdx.x;
  const int tx = tid & 15, ty = tid >> 4;
  const int row0 = blk * 128;
  float acc[8][8];
#pragma unroll
  for (int r = 0; r < 8; ++r)
#pragma unroll
    for (int c = 0; c < 8; ++c) acc[r][c] = 0.f;

  for (int kk = 0; kk < DIM; kk += 16) {
#pragma unroll
    for (int p = 0; p < 2; ++p) {
      int r = (tid >> 2) + p * 64;
      int kc = (tid & 3) * 4;
      float4 a = make_float4(0.f, 0.f, 0.f, 0.f);
      int row = row0 + r;
      if (row < M) a = *(const float4*)(A + (size_t)row * DIM + kk + kc);
      As[kc + 0][r] = a.x; As[kc + 1][r] = a.y; As[kc + 2][r] = a.z; As[kc + 3][r] = a.w;
    }
    {
      const float4* srcp = (const float4*)(W + kk * DIM);
      float4* dstp = (float4*)(&Bs[0][0]);
      dstp[tid]       = srcp[tid];
      dstp[tid + 256] = srcp[tid + 256];
    }
    __syncthreads();
#pragma unroll
    for (int k = 0; k < 16; ++k) {
      float a[8], b[8];
      *(float4*)&a[0] = *(const float4*)&As[k][ty * 8];
      *(float4*)&a[4] = *(const float4*)&As[k][ty * 8 + 4];
      *(float4*)&b[0] = *(const float4*)&Bs[k][tx * 8];
      *(float4*)&b[4] = *(const float4*)&Bs[k][tx * 8 + 4];
#pragma unroll
      for (int r = 0; r < 8; ++r)
#pragma unroll
        for (int c = 0; c < 8; ++c) acc[r][c] += a[r] * b[c];
    }
    __syncthreads();
  }
#pragma unroll
  for (int r = 0; r < 8; ++r) {
    int row = row0 + ty * 8 + r;
    if (row < M) {
      float4* cp = (float4*)(C + (size_t)row * DIM + tx * 8);
      cp[0] = make_float4(acc[r][0], acc[r][1], acc[r][2], acc[r][3]);
      cp[1] = make_float4(acc[r][4], acc[r][5], acc[r][6], acc[r][7]);
    }
  }
}

// ---------------- gather one edge list: float4 half-wave partial sums ----------------
__device__ __forceinline__ float4 gather_list(const float* __restrict__ h,
                                              const int* __restrict__ csr,
                                              const float* __restrict__ inv_s,
                                              int e0, int e1, int lane, int half, int sl) {
  float4 acc = make_float4(0.f, 0.f, 0.f, 0.f);
  for (int base = e0; base < e1; base += 64) {
    int m = e1 - base; m = m < 64 ? m : 64;
    int s_l = 0; float w_l = 0.f;
    if (lane < m) { s_l = csr[base + lane]; w_l = inv_s[s_l]; }
    int j = 0;
    for (; j + 8 <= m; j += 8) {
      const int eb = j + half * 4;
      int s0 = __shfl(s_l, eb),     s1 = __shfl(s_l, eb + 1);
      int s2 = __shfl(s_l, eb + 2), s3 = __shfl(s_l, eb + 3);
      float w0 = __shfl(w_l, eb),     w1 = __shfl(w_l, eb + 1);
      float w2 = __shfl(w_l, eb + 2), w3 = __shfl(w_l, eb + 3);
      float4 v0 = ((const float4*)(h + (size_t)s0 * DIM))[sl];
      float4 v1 = ((const float4*)(h + (size_t)s1 * DIM))[sl];
      float4 v2 = ((const float4*)(h + (size_t)s2 * DIM))[sl];
      float4 v3 = ((const float4*)(h + (size_t)s3 * DIM))[sl];
      acc.x += w0 * v0.x + w1 * v1.x + w2 * v2.x + w3 * v3.x;
      acc.y += w0 * v0.y + w1 * v1.y + w2 * v2.y + w3 * v3.y;
      acc.z += w0 * v0.z + w1 * v1.z + w2 * v2.z + w3 * v3.z;
      acc.w += w0 * v0.w + w1 * v1.w + w2 * v2.w + w3 * v3.w;
    }
    for (; j < m; j += 2) {
      const int e = j + half;   // lanes >= m hold s=0,w=0 -> harmless
      int s = __shfl(s_l, e);
      float w = __shfl(w_l, e);
      float4 v = ((const float4*)(h + (size_t)s * DIM))[sl];
      acc.x += w * v.x; acc.y += w * v.y; acc.z += w * v.z; acc.w += w * v.w;
    }
  }
  return acc;
}

// ---------------- dual-relation layer kernel ----------------
// blocks [0,AGU):  outU[row] = maybe_relu(0.5*(invfd*sumF + invvd*sumV + bA + bB))
// blocks [AGU,..): outI[row] = maybe_relu(invrd*sumR + bR)
template <bool RELU>
__global__ __launch_bounds__(256) void aggL_kernel(
    const float* __restrict__ hf, const int* __restrict__ rpf, const int* __restrict__ csf,
    const float* __restrict__ invfs, const float* __restrict__ invfd,
    const float* __restrict__ hv, const int* __restrict__ rpv, const int* __restrict__ csv,
    const float* __restrict__ invvs, const float* __restrict__ invvd,
    const float* __restrict__ bA, const float* __restrict__ bB, float* __restrict__ outU,
    const float* __restrict__ hr, const int* __restrict__ rpr, const int* __restrict__ csp,
    const float* __restrict__ invrs, const float* __restrict__ invrd,
    const float* __restrict__ bR, float* __restrict__ outI) {
  const int lane = threadIdx.x & 63;
  const int half = lane >> 5;
  const int sl   = lane & 31;
  const int b = blockIdx.x;
  if (b < AGU) {
    const int row = b * 4 + (threadIdx.x >> 6);
    if (row >= NU) return;
    float4 aF = gather_list(hf, csf, invfs, rpf[row], rpf[row + 1], lane, half, sl);
    float4 aV = gather_list(hv, csv, invvs, rpv[row], rpv[row + 1], lane, half, sl);
    const float df = invfd[row], dv = invvd[row];
    float4 t;
    t.x = df * aF.x + dv * aV.x;
    t.y = df * aF.y + dv * aV.y;
    t.z = df * aF.z + dv * aV.z;
    t.w = df * aF.w + dv * aV.w;
    float4 o;
    o.x = __shfl(t.x, lane ^ 32); o.y = __shfl(t.y, lane ^ 32);
    o.z = __shfl(t.z, lane ^ 32); o.w = __shfl(t.w, lane ^ 32);
    t.x += o.x; t.y += o.y; t.z += o.z; t.w += o.w;
    if (half == 0) {
      float4 ba = ((const float4*)bA)[sl];
      float4 bb = ((const float4*)bB)[sl];
      float4 v;
      v.x = 0.5f * (t.x + ba.x + bb.x);
      v.y = 0.5f * (t.y + ba.y + bb.y);
      v.z = 0.5f * (t.z + ba.z + bb.z);
      v.w = 0.5f * (t.w + ba.w + bb.w);
      if (RELU) {
        v.x = fmaxf(v.x, 0.f); v.y = fmaxf(v.y, 0.f);
        v.z = fmaxf(v.z, 0.f); v.w = fmaxf(v.w, 0.f);
      }
      ((float4*)(outU + (size_t)row * DIM))[sl] = v;
    }
  } else {
    const int row = (b - AGU) * 4 + (threadIdx.x >> 6);
    if (row >= NI) return;
    float4 aR = gather_list(hr, csp, invrs, rpr[row], rpr[row + 1], lane, half, sl);
    const float dr = invrd[row];
    float4 t = make_float4(dr * aR.x, dr * aR.y, dr * aR.z, dr * aR.w);
    float4 o;
    o.x = __shfl(t.x, lane ^ 32); o.y = __shfl(t.y, lane ^ 32);
    o.z = __shfl(t.z, lane ^ 32); o.w = __shfl(t.w, lane ^ 32);
    t.x += o.x; t.y += o.y; t.z += o.z; t.w += o.w;
    if (half == 0) {
      float4 br4 = ((const float4*)bR)[sl];
      float4 v = make_float4(t.x + br4.x, t.y + br4.y, t.z + br4.z, t.w + br4.w);
      if (RELU) {
        v.x = fmaxf(v.x, 0.f); v.y = fmaxf(v.y, 0.f);
        v.z = fmaxf(v.z, 0.f); v.w = fmaxf(v.w, 0.f);
      }
      ((float4*)(outI + (size_t)row * DIM))[sl] = v;
    }
  }
}

// ---------------- single-list MODE agg (fallback path; proven in round 6) ----------------
template <int MODE, bool RELU>
__device__ __forceinline__ void agg_rows(const float* __restrict__ h, const int* __restrict__ rp,
                                         const int* __restrict__ csr, const float* __restrict__ inv_s,
                                         const float* __restrict__ inv_d, float* __restrict__ out,
                                         int n_dst, float scale, const float* __restrict__ b1,
                                         const float* __restrict__ b2, int blk) {
  const int lane = threadIdx.x & 63;
  const int half = lane >> 5;
  const int sl   = lane & 31;
  const int row = blk * 4 + (threadIdx.x >> 6);
  if (row >= n_dst) return;
  float4 acc = gather_list(h, csr, inv_s, rp[row], rp[row + 1], lane, half, sl);
  float4 o;
  o.x = __shfl(acc.x, lane ^ 32); o.y = __shfl(acc.y, lane ^ 32);
  o.z = __shfl(acc.z, lane ^ 32); o.w = __shfl(acc.w, lane ^ 32);
  acc.x += o.x; acc.y += o.y; acc.z += o.z; acc.w += o.w;
  if (half == 0) {
    const float invd = inv_d[row];
    float4 r = make_float4(acc.x * invd, acc.y * invd, acc.z * invd, acc.w * invd);
    float4* op4 = (float4*)(out + (size_t)row * DIM);
    if (MODE == 0) {
      op4[sl] = r;
    } else {
      float4 bv = make_float4(0.f, 0.f, 0.f, 0.f);
      if (b1) { float4 b = ((const float4*)b1)[sl]; bv.x += b.x; bv.y += b.y; bv.z += b.z; bv.w += b.w; }
      if (b2) { float4 b = ((const float4*)b2)[sl]; bv.x += b.x; bv.y += b.y; bv.z += b.z; bv.w += b.w; }
      float4 p = make_float4(0.f, 0.f, 0.f, 0.f);
      if (MODE == 1) p = op4[sl];
      float4 v;
      v.x = scale * (p.x + r.x + bv.x);
      v.y = scale * (p.y + r.y + bv.y);
      v.z = scale * (p.z + r.z + bv.z);
      v.w = scale * (p.w + r.w + bv.w);
      if (RELU) {
        v.x = fmaxf(v.x, 0.f); v.y = fmaxf(v.y, 0.f);
        v.z = fmaxf(v.z, 0.f); v.w = fmaxf(v.w, 0.f);
      }
      op4[sl] = v;
    }
  }
}

template <int MODE, bool RELU>
__global__ __launch_bounds__(256) void agg_kernel(const float* h, const int* rp, const int* csr,
                                                  const float* inv_s, const float* inv_d,
                                                  float* out, int n_dst, float scale,
                                                  const float* b1, const float* b2) {
  agg_rows<MODE, RELU>(h, rp, csr, inv_s, inv_d, out, n_dst, scale, b1, b2, blockIdx.x);
}

// ---------------- single-block scan body ----------------
__device__ void scan_body(const int* __restrict__ deg, int n, int* __restrict__ rp) {
  static __shared__ int wsum[16];
  static __shared__ int carry_s;
  const int tid = threadIdx.x, lane = tid & 63, wid = tid >> 6;
  if (tid == 0) carry_s = 0;
  __syncthreads();
  for (int base = 0; base < n; base += 4096) {
    int i0 = base + tid * 4;
    int v0 = 0, v1 = 0, v2 = 0, v3 = 0;
    if (i0 + 3 < n) {
      int4 t = *(const int4*)(deg + i0);
      v0 = t.x; v1 = t.y; v2 = t.z; v3 = t.w;
    } else {
      if (i0     < n) v0 = deg[i0];
      if (i0 + 1 < n) v1 = deg[i0 + 1];
      if (i0 + 2 < n) v2 = deg[i0 + 2];
    }
    int s0 = v0, s1 = s0 + v1, s2 = s1 + v2, s3 = s2 + v3;
    int tot = s3;
    int x = tot;
#pragma unroll
    for (int d2 = 1; d2 < 64; d2 <<= 1) { int y = __shfl_up(x, d2); if (lane >= d2) x += y; }
    if (lane == 63) wsum[wid] = x;
    __syncthreads();
    if (wid == 0) {
      int s = (lane < 16) ? wsum[lane] : 0;
#pragma unroll
      for (int d2 = 1; d2 < 16; d2 <<= 1) { int y = __shfl_up(s, d2); if (lane >= d2) s += y; }
      if (lane < 16) wsum[lane] = s;
    }
    __syncthreads();
    int carry = carry_s;
    int woff = (wid > 0) ? wsum[wid - 1] : 0;
    int base_excl = carry + woff + (x - tot);
    if (i0     < n) rp[i0]     = base_excl;
    if (i0 + 1 < n) rp[i0 + 1] = base_excl + s0;
    if (i0 + 2 < n) rp[i0 + 2] = base_excl + s1;
    if (i0 + 3 < n) rp[i0 + 3] = base_excl + s2;
    __syncthreads();
    if (tid == 0) carry_s = carry + wsum[15];
    __syncthreads();
  }
  if (tid == 0) rp[n] = carry_s;
}

// =================== top-level kernels ===================

__global__ __launch_bounds__(256) void count3_kernel(
    const int* f_src, const int* f_dst, int* deg_fs, int* deg_fd, int* rank_f,
    const int* r_src, const int* r_dst, int* deg_rs, int* deg_rd, int* rank_r,
    const int* v_src, const int* v_dst, int* deg_vs, int* deg_vd, int* rank_v) {
  int b = blockIdx.x;
  if (b < C3)          count_rel(f_src, f_dst, deg_fs, deg_fd, rank_f, b, C3);
  else if (b < 2 * C3) count_rel(r_src, r_dst, deg_rs, deg_rd, rank_r, b - C3, C3);
  else                 count_rel(v_src, v_dst, deg_vs, deg_vd, rank_v, b - 2 * C3, C3);
}

__global__ __launch_bounds__(256) void fill3_kernel(
    const int* f_src, const int* f_dst, const int* rank_f, const int* rp_f, int* csr_f,
    const int* r_src, const int* r_dst, const int* rank_r, const int* rp_r, int* csr_r,
    const int* v_src, const int* v_dst, const int* rank_v, const int* rp_v, int* csr_v) {
  int b = blockIdx.x;
  if (b < F3)          fill_rel(f_src, f_dst, rank_f, rp_f, csr_f, b, F3);
  else if (b < 2 * F3) fill_rel(r_src, r_dst, rank_r, rp_r, csr_r, b - F3, F3);
  else                 fill_rel(v_src, v_dst, rank_v, rp_v, csr_v, b - 2 * F3, F3);
}

__global__ __launch_bounds__(1024) void scan3_kernel(const int* deg_fd, int* rp_f,
                                                     const int* deg_rd, int* rp_r,
                                                     const int* deg_vd, int* rp_v) {
  if (blockIdx.x == 0)      scan_body(deg_fd, NU, rp_f);
  else if (blockIdx.x == 1) scan_body(deg_rd, NI, rp_r);
  else                      scan_body(deg_vd, NU, rp_v);
}

__global__ void inv_sqrt_kernel(int* __restrict__ p, int n) {
  int i = blockIdx.x * blockDim.x + threadIdx.x;
  if (i < n) {
    int v = p[i];
    float f = (v > 0) ? (1.0f / sqrtf((float)v)) : 0.0f;
    p[i] = __float_as_int(f);
  }
}

// three independent 128x128-weight GEMMs in one launch (slot sizes GF / GV / GF)
__global__ __launch_bounds__(256) void gemm3_kernel(
    const float* A0, const float* W0, float* C0,
    const float* A1, const float* W1, float* C1,
    const float* A2, const float* W2, float* C2) {
  int b = blockIdx.x;
  if (b < GF)           gemm_body(A0, W0, C0, NU, b);
  else if (b < GF + GV) gemm_body(A1, W1, C1, NI, b - GF);
  else                  gemm_body(A2, W2, C2, NU, b - GF - GV);
}

__global__ __launch_bounds__(256) void gemm_one_kernel(const float* A, const float* W, float* C, int M) {
  gemm_body(A, W, C, M, blockIdx.x);
}

extern "C" void kernel_launch(void* const* d_in, const int* in_sizes, int n_in,
                              void* d_out, int out_size, void* d_ws, size_t ws_size,
                              hipStream_t stream) {
  const float* x_user = (const float*)d_in[0];
  const float* x_item = (const float*)d_in[1];
  const int* f_src = (const int*)d_in[2];
  const int* f_dst = (const int*)d_in[3];
  const int* r_src = (const int*)d_in[4];
  const int* r_dst = (const int*)d_in[5];
  const int* v_src = (const int*)d_in[6];
  const int* v_dst = (const int*)d_in[7];
  const float* W1f = (const float*)d_in[8];
  const float* W1r = (const float*)d_in[9];
  const float* W1v = (const float*)d_in[10];
  const float* W2f = (const float*)d_in[11];
  const float* W2r = (const float*)d_in[12];
  const float* W2v = (const float*)d_in[13];
  const float* b1f = (const float*)d_in[14];
  const float* b1r = (const float*)d_in[15];
  const float* b1v = (const float*)d_in[16];
  const float* b2f = (const float*)d_in[17];
  const float* b2r = (const float*)d_in[18];
  const float* b2v = (const float*)d_in[19];
  (void)in_sizes; (void)n_in; (void)out_size;

  char* ws = (char*)d_ws;
  size_t off = 0;
  auto alloc = [&](size_t bytes) {
    size_t o = off;
    off = (off + bytes + 511) & ~(size_t)511;
    return o;
  };
  size_t o_deg = alloc(4ull * (4 * NU + 2 * NI));
  size_t o_rpf = alloc(4ull * (NU + 1));
  size_t o_rpr = alloc(4ull * (NI + 1));
  size_t o_rpv = alloc(4ull * (NU + 1));
  size_t o_csf = alloc(4ull * NEDGE);
  size_t o_csr = alloc(4ull * NEDGE);
  size_t o_csv = alloc(4ull * NEDGE);
  size_t o_it  = alloc(4ull * NI * DIM);
  size_t o_hf  = alloc(4ull * NU * DIM);
  size_t o_u   = alloc(4ull * NU * DIM);
  size_t o_hv  = alloc(4ull * NI * DIM);
  size_t o_hr  = alloc(4ull * NU * DIM);
  size_t o_rkf = alloc(4ull * NEDGE);
  size_t o_rkr = alloc(4ull * NEDGE);
  size_t o_rkv = alloc(4ull * NEDGE);
  size_t big_need = off + 512;

  const bool big = (ws_size >= big_need);

  int* deg    = (int*)(ws + o_deg);
  int* deg_fs = deg;
  int* deg_fd = deg + NU;
  int* deg_rs = deg + 2 * NU;
  int* deg_rd = deg + 3 * NU;
  int* deg_vs = deg + 3 * NU + NI;
  int* deg_vd = deg + 3 * NU + 2 * NI;

  int* rp_f = (int*)(ws + o_rpf);
  int* rp_r = (int*)(ws + o_rpr);
  int* rp_v = (int*)(ws + o_rpv);
  int* csr_f = (int*)(ws + o_csf);
  int* csr_r = (int*)(ws + o_csr);
  int* csr_v = (int*)(ws + o_csv);
  float* it  = (float*)(ws + o_it);
  float* h_f = (float*)(ws + o_hf);
  float* u   = (float*)(ws + o_u);
  float* h_v = big ? (float*)(ws + o_hv) : h_f;
  float* h_r = big ? (float*)(ws + o_hr) : h_f;
  // fallback: ranks alias u (consumed by fill3 before u is first written)
  int* rank_f = big ? (int*)(ws + o_rkf) : (int*)(ws + o_u);
  int* rank_r = big ? (int*)(ws + o_rkr) : (int*)(ws + o_u) + NEDGE;
  int* rank_v = big ? (int*)(ws + o_rkv) : (int*)(ws + o_u) + 2 * NEDGE;

  float* out_u = (float*)d_out;
  float* out_i = out_u + (size_t)NU * DIM;

  const float* inv_fs = (const float*)deg_fs;
  const float* inv_fd = (const float*)deg_fd;
  const float* inv_rs = (const float*)deg_rs;
  const float* inv_rd = (const float*)deg_rd;
  const float* inv_vs = (const float*)deg_vs;
  const float* inv_vd = (const float*)deg_vd;

  hipMemsetAsync(deg, 0, 4ull * (4 * NU + 2 * NI), stream);

  // CSR build (shared by both paths)
  count3_kernel<<<3 * C3, 256, 0, stream>>>(
      f_src, f_dst, deg_fs, deg_fd, rank_f,
      r_src, r_dst, deg_rs, deg_rd, rank_r,
      v_src, v_dst, deg_vs, deg_vd, rank_v);
  scan3_kernel<<<3, 1024, 0, stream>>>(deg_fd, rp_f, deg_rd, rp_r, deg_vd, rp_v);
  inv_sqrt_kernel<<<(4 * NU + 2 * NI + 1023) / 1024, 1024, 0, stream>>>(deg, 4 * NU + 2 * NI);
  fill3_kernel<<<3 * F3, 256, 0, stream>>>(
      f_src, f_dst, rank_f, rp_f, csr_f,
      r_src, r_dst, rank_r, rp_r, csr_r,
      v_src, v_dst, rank_v, rp_v, csr_v);

  if (big) {
    // layer 1: three GEMMs in one launch, then fused dual-agg + item agg in one launch
    gemm3_kernel<<<GF + GV + GF, 256, 0, stream>>>(
        x_user, W1f, h_f, x_item, W1v, h_v, x_user, W1r, h_r);
    aggL_kernel<true><<<AGU + AGI, 256, 0, stream>>>(
        h_f, rp_f, csr_f, inv_fs, inv_fd,
        h_v, rp_v, csr_v, inv_vs, inv_vd,
        b1f, b1v, u,
        h_r, rp_r, csr_r, inv_rs, inv_rd, b1r, it);
    // layer 2: identical structure, no relu, into d_out
    gemm3_kernel<<<GF + GV + GF, 256, 0, stream>>>(
        u, W2f, h_f, it, W2v, h_v, u, W2r, h_r);
    aggL_kernel<false><<<AGU + AGI, 256, 0, stream>>>(
        h_f, rp_f, csr_f, inv_fs, inv_fd,
        h_v, rp_v, csr_v, inv_vs, inv_vd,
        b2f, b2v, out_u,
        h_r, rp_r, csr_r, inv_rs, inv_rd, b2r, out_i);
  } else {
    // sequential fallback, single h buffer
    gemm_one_kernel<<<GF, 256, 0, stream>>>(x_user, W1f, h_f, NU);
    agg_kernel<0, false><<<AGU, 256, 0, stream>>>(h_f, rp_f, csr_f, inv_fs, inv_fd, u, NU, 1.0f, nullptr, nullptr);
    gemm_one_kernel<<<GV, 256, 0, stream>>>(x_item, W1v, h_f, NI);
    agg_kernel<1, true><<<AGU, 256, 0, stream>>>(h_f, rp_v, csr_v, inv_vs, inv_vd, u, NU, 0.5f, b1f, b1v);
    gemm_one_kernel<<<GF, 256, 0, stream>>>(x_user, W1r, h_f, NU);
    agg_kernel<2, true><<<AGI, 256, 0, stream>>>(h_f, rp_r, csr_r, inv_rs, inv_rd, it, NI, 1.0f, b1r, nullptr);
    gemm_one_kernel<<<GF, 256, 0, stream>>>(u, W2f, h_f, NU);
    agg_kernel<0, false><<<AGU, 256, 0, stream>>>(h_f, rp_f, csr_f, inv_fs, inv_fd, out_u, NU, 1.0f, nullptr, nullptr);
    gemm_one_kernel<<<GV, 256, 0, stream>>>(it, W2v, h_f, NI);
    agg_kernel<1, false><<<AGU, 256, 0, stream>>>(h_f, rp_v, csr_v, inv_vs, inv_vd, out_u, NU, 0.5f, b2f, b2v);
    gemm_one_kernel<<<GF, 256, 0, stream>>>(u, W2r, h_f, NU);
    agg_kernel<2, false><<<AGI, 256, 0, stream>>>(h_f, rp_r, csr_r, inv_rs, inv_rd, out_i, NI, 1.0f, b2r, nullptr);
  }
}